// Round 7
// baseline (2920.567 us; speedup 1.0000x reference)
//
#include <hip/hip_runtime.h>
#include <hip/hip_bf16.h>

// Sinkhorn entropic OT (reg=1, 100 iters), persistent kernel + dataflow sync,
// int8 L2-resident cost matrix.
//   Zq = round(2*log2e*(x.yT)/4)+128 (u8, 16MiB), ZTq likewise -> per-XCD
//   working set 4MiB = L2 capacity. Dequant: Z = 4*q - 512.
//   f: fcore_i = LOG2A - log2 sum_j 2^(gcore_j + Z_ij)     (even phases)
//   g: gcore_j = LOG2A - log2 sum_i 2^(fcore_i + ZT_ji)    (odd phases)
// Slots: u64 (tag<<32 | f32 bits), relaxed AGENT-scope atomics (L3, no
// L2-invalidating fences). Exact-tag spin; all-to-all dep bounds skew < 2
// phases -> single buffer race-free (read-before-publish causality).
// uu double-buffered in LDS (idx swizzle col+(col>>5) kills 8-way conflicts).
// out = ln2/(N*D) * [ sum_i 2^(fcore-php)*(fcore+ax-LOG2A) + sum_j (gcore+ay-LOG2A) ]

#define N 4096
#define D 1024
#define L2E 1.4426950408889634f
#define LOG2A (-12.0f)
#define NBLK 256
#define NPHASE 201   // 100*(f,g) + final f (row marginals)

typedef unsigned char u8;
typedef unsigned short u16;
typedef unsigned long long u64;
typedef __attribute__((ext_vector_type(8))) short bf16x8;
typedef __attribute__((ext_vector_type(4))) float f32x4;

#define ALOAD64(p)     __hip_atomic_load((p), __ATOMIC_RELAXED, __HIP_MEMORY_SCOPE_AGENT)
#define ASTORE64(p, v) __hip_atomic_store((p), (v), __ATOMIC_RELAXED, __HIP_MEMORY_SCOPE_AGENT)

static __device__ inline u64 pack(unsigned tag, float v) {
  return ((u64)tag << 32) | (u64)__float_as_uint(v);
}

static __device__ inline u16 f2bf(float f) {
  unsigned u = __float_as_uint(f);
  unsigned r = (u + 0x7FFFu + ((u >> 16) & 1u)) >> 16;
  return (u16)r;
}

static __device__ inline void gload_lds16(const void* g, void* l) {
  __builtin_amdgcn_global_load_lds(
      (const __attribute__((address_space(1))) void*)g,
      (__attribute__((address_space(3))) void*)l, 16, 0, 0);
}

static __device__ inline int swz(int col) { return col + (col >> 5); }

// ---- prep: row sum-of-squares + fp32->bf16 + ax/ay + slot init (replay-safe)
__global__ __launch_bounds__(256) void prep_kernel(
    const float* __restrict__ x, const float* __restrict__ y,
    u16* __restrict__ xb, u16* __restrict__ yb,
    float* __restrict__ ax, float* __restrict__ ay,
    u64* __restrict__ fsl, u64* __restrict__ gsl, u64* __restrict__ psl)
{
  int rb = blockIdx.x;
  bool isY = rb >= N;
  int row = isY ? rb - N : rb;
  const float4* src = (const float4*)((isY ? y : x) + (size_t)row * D);
  u16* dst = (isY ? yb : xb) + (size_t)row * D;
  int t = threadIdx.x;

  if (!isY && t == 0) {            // reset tags every call (graph-replay safe)
    ASTORE64(&fsl[row], 0ull);
    ASTORE64(&psl[row], 0ull);
  }

  float4 v = src[t];
  float ss = v.x * v.x + v.y * v.y + v.z * v.z + v.w * v.w;
  ushort4 h;
  h.x = f2bf(v.x); h.y = f2bf(v.y); h.z = f2bf(v.z); h.w = f2bf(v.w);
  ((ushort4*)dst)[t] = h;

  #pragma unroll
  for (int o = 1; o < 64; o <<= 1) ss += __shfl_xor(ss, o, 64);
  __shared__ float sred[4];
  if ((t & 63) == 0) sred[t >> 6] = ss;
  __syncthreads();
  if (t == 0) {
    float a = (sred[0] + sred[1] + sred[2] + sred[3]) * L2E;
    if (isY) { ay[row] = a; ASTORE64(&gsl[row], pack(0u, LOG2A - a)); }
    else     { ax[row] = a; }
  }
}

// ---- GEMM: Zq[i][j] = clamp(round(2*log2e*(A_i.B_j)/4)+128), bf16 MFMA 128x128
__global__ __launch_bounds__(256) void gemm_s(
    const u16* __restrict__ A, const u16* __restrict__ B, u8* __restrict__ out)
{
  __shared__ u16 As[128 * 64];
  __shared__ u16 Bs[128 * 64];
  const int t = threadIdx.x;
  const int lane = t & 63, w = t >> 6;
  const int wm = w >> 1, wn = w & 1;
  const int i0 = blockIdx.y * 128, j0 = blockIdx.x * 128;

  f32x4 acc[4][4] = {};

  for (int k0 = 0; k0 < D; k0 += 64) {
    #pragma unroll
    for (int q = 0; q < 4; ++q) {
      int lin = q * 256 + t;
      int row = lin >> 3, c8 = lin & 7;
      int cs = c8 ^ (row & 7);
      gload_lds16(A + (size_t)(i0 + row) * D + k0 + cs * 8, ((char*)As) + q * 4096 + w * 1024);
      gload_lds16(B + (size_t)(j0 + row) * D + k0 + cs * 8, ((char*)Bs) + q * 4096 + w * 1024);
    }
    __syncthreads();
    #pragma unroll
    for (int kk = 0; kk < 2; ++kk) {
      bf16x8 af[4], bfr[4];
      const int g = lane >> 4;
      #pragma unroll
      for (int fm = 0; fm < 4; ++fm) {
        int r = wm * 64 + fm * 16 + (lane & 15);
        af[fm] = *(const bf16x8*)(((const char*)As) + r * 128 + (((kk * 4 + g) ^ (r & 7)) * 16));
      }
      #pragma unroll
      for (int fn = 0; fn < 4; ++fn) {
        int r = wn * 64 + fn * 16 + (lane & 15);
        bfr[fn] = *(const bf16x8*)(((const char*)Bs) + r * 128 + (((kk * 4 + g) ^ (r & 7)) * 16));
      }
      #pragma unroll
      for (int fm = 0; fm < 4; ++fm)
        #pragma unroll
        for (int fn = 0; fn < 4; ++fn)
          acc[fm][fn] = __builtin_amdgcn_mfma_f32_16x16x32_bf16(af[fm], bfr[fn], acc[fm][fn], 0, 0, 0);
    }
    __syncthreads();
  }

  const float QS = 2.0f * L2E * 0.25f;   // acc * 2*log2e / 4
  #pragma unroll
  for (int fm = 0; fm < 4; ++fm)
    #pragma unroll
    for (int fn = 0; fn < 4; ++fn) {
      int gj = j0 + wn * 64 + fn * 16 + (lane & 15);
      #pragma unroll
      for (int r = 0; r < 4; ++r) {
        int gi = i0 + wm * 64 + fm * 16 + (lane >> 4) * 4 + r;
        int q = (int)rintf(acc[fm][fn][r] * QS) + 128;
        q = q < 0 ? 0 : (q > 255 ? 255 : q);
        out[(size_t)gi * N + gj] = (u8)q;
      }
    }
}

// process 16 cols of one chunk: vv[k] = 4*q_k + uu'_k, track max
static __device__ inline void chunk16(uint4 zz, const float* up, float* vv, float& m) {
  unsigned dw0 = zz.x, dw1 = zz.y, dw2 = zz.z, dw3 = zz.w;
  #pragma unroll
  for (int b = 0; b < 4; ++b) {
    unsigned d = (b == 0) ? dw0 : (b == 1) ? dw1 : (b == 2) ? dw2 : dw3;
    float v0 = fmaf((float)(d & 0xffu),         4.0f, up[b * 4 + 0]);
    float v1 = fmaf((float)((d >> 8) & 0xffu),  4.0f, up[b * 4 + 1]);
    float v2 = fmaf((float)((d >> 16) & 0xffu), 4.0f, up[b * 4 + 2]);
    float v3 = fmaf((float)(d >> 24),           4.0f, up[b * 4 + 3]);
    vv[b * 4 + 0] = v0; vv[b * 4 + 1] = v1; vv[b * 4 + 2] = v2; vv[b * 4 + 3] = v3;
    m = fmaxf(m, fmaxf(fmaxf(v0, v1), fmaxf(v2, v3)));
  }
}

// ---- persistent Sinkhorn, row-per-wave, dataflow-synced, int8 matrix
__global__ __launch_bounds__(1024, 4) void sinkhorn_persist(
    const u8* __restrict__ Zq, const u8* __restrict__ ZTq,
    const float* __restrict__ ax, const float* __restrict__ ay,
    u64* __restrict__ fsl, u64* __restrict__ gsl, u64* __restrict__ psl,
    float* __restrict__ out)
{
  __shared__ float uu[2][4096 + 128];
  __shared__ float sred[16];
  const int t = threadIdx.x, blk = blockIdx.x;
  const int w = t >> 6, lane = t & 63;
  const int row = blk * 16 + w;                        // wave w owns row `row`
  const size_t zbase = (size_t)row * N + (lane << 4);  // bytes; chunks at +1024

  // swizzled LDS read bases (contiguous 16 floats each; col 16-aligned)
  int ub[4];
  #pragma unroll
  for (int c = 0; c < 4; ++c) ub[c] = swz(c * 1024 + (lane << 4));

  uint4 zq[4];
  {
    const uint4* zp = (const uint4*)(Zq + zbase);
    #pragma unroll
    for (int c = 0; c < 4; ++c) zq[c] = zp[c * 64];
  }
  // initial stage: phase 0 inputs = gsl tag 0
  {
    u64 sv[4];
    #pragma unroll
    for (int k = 0; k < 4; ++k) sv[k] = ALOAD64(&gsl[4 * t + k]);
    #pragma unroll
    for (int k = 0; k < 4; ++k) {
      while ((unsigned)(sv[k] >> 32) != 0u) {
        __builtin_amdgcn_s_sleep(1);
        sv[k] = ALOAD64(&gsl[4 * t + k]);
      }
      uu[0][swz(4 * t + k)] = __uint_as_float((unsigned)sv[k]) - 512.0f;
    }
  }
  __syncthreads();

  for (int ph = 0; ph < NPHASE; ++ph) {
    const int cur = ph & 1;
    u64* vsl = (ph == NPHASE - 1) ? psl : ((ph & 1) ? gsl : fsl);

    // half A: chunks 0,1
    float vv[32];
    float mA = -3.0e38f;
    chunk16(zq[0], &uu[cur][ub[0]], vv, mA);
    chunk16(zq[1], &uu[cur][ub[1]], vv + 16, mA);
    float sA = 0.0f;
    #pragma unroll
    for (int k = 0; k < 32; ++k) sA += exp2f(vv[k] - mA);
    // half B: chunks 2,3 (reuse vv)
    float mB = -3.0e38f;
    chunk16(zq[2], &uu[cur][ub[2]], vv, mB);
    chunk16(zq[3], &uu[cur][ub[3]], vv + 16, mB);
    float sB = 0.0f;
    #pragma unroll
    for (int k = 0; k < 32; ++k) sB += exp2f(vv[k] - mB);

    float m = fmaxf(mA, mB);
    float s = sA * exp2f(mA - m) + sB * exp2f(mB - m);
    #pragma unroll
    for (int o = 1; o < 64; o <<= 1) {
      float mo = __shfl_xor(m, o, 64);
      float so = __shfl_xor(s, o, 64);
      float mn = fmaxf(m, mo);
      s = s * exp2f(m - mn) + so * exp2f(mo - mn);
      m = mn;
    }
    if (lane == 0)
      ASTORE64(&vsl[row], pack((unsigned)(ph + 1), LOG2A - (m + log2f(s))));

    if (ph + 1 < NPHASE) {
      // next phase's matrix slice (L2-resident int8) + input staging
      const u8* Mn = ((ph + 1) & 1) ? ZTq : Zq;
      const uint4* zp = (const uint4*)(Mn + zbase);
      #pragma unroll
      for (int c = 0; c < 4; ++c) zq[c] = zp[c * 64];

      const u64* vinN = ((ph + 1) & 1) ? fsl : gsl;
      const int nxt = (ph + 1) & 1;
      u64 sv[4];
      #pragma unroll
      for (int k = 0; k < 4; ++k) sv[k] = ALOAD64(&vinN[4 * t + k]);
      #pragma unroll
      for (int k = 0; k < 4; ++k) {
        while ((unsigned)(sv[k] >> 32) != (unsigned)(ph + 1)) {
          __builtin_amdgcn_s_sleep(1);
          sv[k] = ALOAD64(&vinN[4 * t + k]);
        }
        uu[nxt][swz(4 * t + k)] = __uint_as_float((unsigned)sv[k]) - 512.0f;
      }
      __syncthreads();
    }
  }

  // finalize: block 0 gathers (spins until every block's last outputs land)
  if (blk == 0) {
    float acc = 0.0f;
    #pragma unroll
    for (int rep = 0; rep < 4; ++rep) {
      int i = (rep << 10) + t;
      u64 vf = ALOAD64(&fsl[i]);
      while ((unsigned)(vf >> 32) != (unsigned)(NPHASE - 2)) { __builtin_amdgcn_s_sleep(1); vf = ALOAD64(&fsl[i]); }
      u64 vg = ALOAD64(&gsl[i]);
      while ((unsigned)(vg >> 32) != (unsigned)(NPHASE - 1)) { __builtin_amdgcn_s_sleep(1); vg = ALOAD64(&gsl[i]); }
      u64 vp = ALOAD64(&psl[i]);
      while ((unsigned)(vp >> 32) != (unsigned)(NPHASE))     { __builtin_amdgcn_s_sleep(1); vp = ALOAD64(&psl[i]); }
      float fc = __uint_as_float((unsigned)vf);
      float gc = __uint_as_float((unsigned)vg);
      float pp = __uint_as_float((unsigned)vp);
      acc += exp2f(fc - pp) * (fc + ax[i] - LOG2A);
      acc += gc + ay[i] - LOG2A;
    }
    #pragma unroll
    for (int o = 1; o < 64; o <<= 1) acc += __shfl_xor(acc, o, 64);
    if ((t & 63) == 0) sred[t >> 6] = acc;
    __syncthreads();
    if (t == 0) {
      float tot = 0.0f;
      #pragma unroll
      for (int k = 0; k < 16; ++k) tot += sred[k];
      const float LN2 = 0.6931471805599453f;
      out[0] = tot * (LN2 / ((float)N * (float)D));
    }
  }
}

extern "C" void kernel_launch(void* const* d_in, const int* in_sizes, int n_in,
                              void* d_out, int out_size, void* d_ws, size_t ws_size,
                              hipStream_t stream) {
  const float* x = (const float*)d_in[0];
  const float* y = (const float*)d_in[1];
  float* out = (float*)d_out;
  char* ws = (char*)d_ws;

  const size_t SZ_Q  = (size_t)N * N * sizeof(u8);    // 16 MiB
  const size_t SZ_BF = (size_t)N * D * sizeof(u16);   // 8 MiB
  const size_t SZ_V  = (size_t)N * sizeof(float);     // 16 KiB
  const size_t SZ_S  = (size_t)N * sizeof(u64);       // 32 KiB

  u8*  Zq  = (u8*)(ws);
  u8*  ZTq = (u8*)(ws + SZ_Q);
  u16* xb  = (u16*)(ws + 2 * SZ_Q);
  u16* yb  = (u16*)(ws + 2 * SZ_Q + SZ_BF);
  char* vb = ws + 2 * SZ_Q + 2 * SZ_BF;
  float* ax = (float*)(vb + 0 * SZ_V);
  float* ay = (float*)(vb + 1 * SZ_V);
  u64* fsl  = (u64*)(vb + 2 * SZ_V);
  u64* gsl  = (u64*)(vb + 2 * SZ_V + 1 * SZ_S);
  u64* psl  = (u64*)(vb + 2 * SZ_V + 2 * SZ_S);

  prep_kernel<<<2 * N, 256, 0, stream>>>(x, y, xb, yb, ax, ay, fsl, gsl, psl);

  dim3 gg(N / 128, N / 128, 1);
  gemm_s<<<gg, 256, 0, stream>>>(xb, yb, Zq);
  gemm_s<<<gg, 256, 0, stream>>>(yb, xb, ZTq);

  sinkhorn_persist<<<NBLK, 1024, 0, stream>>>(Zq, ZTq, ax, ay, fsl, gsl, psl, out);
}

// Round 8
// 2060.452 us; speedup vs baseline: 1.4174x; 1.4174x over previous
//
#include <hip/hip_runtime.h>
#include <hip/hip_bf16.h>

// Sinkhorn entropic OT (reg=1, 100 iters), persistent kernel, int8 L2-resident
// cost matrix, per-block FLAG dataflow sync (poll storm removed).
//   Zq = round(2*log2e*(x.yT)/4)+128 (u8, 16MiB), ZTq likewise. Z = 4*q - 512.
//   f: fcore_i = LOG2A - log2 sum_j 2^(gcore_j + Z_ij)     (even phases)
//   g: gcore_j = LOG2A - log2 sum_i 2^(fcore_i + ZT_ji)    (odd phases)
// Protocol per phase: publish 16 fp32 values (relaxed agent atomics) ->
// __syncthreads (drains store-acks) -> t0 stores flags[blk]=ph+1 -> wave0
// polls 256 flags -> barrier -> all threads read the 4096 inputs ONCE.
// Causality: block publishes flag(ph+1) only after staging input(ph), so no
// block can overwrite a value buffer someone still needs (skew < 2 phases).
// out = ln2/(N*D) * [ sum_i 2^(fcore-php)*(fcore+ax-LOG2A) + sum_j (gcore+ay-LOG2A) ]

#define N 4096
#define D 1024
#define L2E 1.4426950408889634f
#define LOG2A (-12.0f)
#define NBLK 256
#define NPHASE 201   // 100*(f,g) + final f (row marginals)

typedef unsigned char u8;
typedef unsigned short u16;
typedef unsigned u32;
typedef unsigned long long u64;
typedef __attribute__((ext_vector_type(8))) short bf16x8;
typedef __attribute__((ext_vector_type(4))) float f32x4;

#define ALOAD(p)     __hip_atomic_load((p), __ATOMIC_RELAXED, __HIP_MEMORY_SCOPE_AGENT)
#define ASTORE(p, v) __hip_atomic_store((p), (v), __ATOMIC_RELAXED, __HIP_MEMORY_SCOPE_AGENT)

static __device__ inline u16 f2bf(float f) {
  unsigned u = __float_as_uint(f);
  unsigned r = (u + 0x7FFFu + ((u >> 16) & 1u)) >> 16;
  return (u16)r;
}

static __device__ inline void gload_lds16(const void* g, void* l) {
  __builtin_amdgcn_global_load_lds(
      (const __attribute__((address_space(1))) void*)g,
      (__attribute__((address_space(3))) void*)l, 16, 0, 0);
}

static __device__ inline int swz(int col) { return col + (col >> 5); }

// ---- prep: row sum-of-squares + fp32->bf16 + ax/ay/gv init + flag reset
__global__ __launch_bounds__(256) void prep_kernel(
    const float* __restrict__ x, const float* __restrict__ y,
    u16* __restrict__ xb, u16* __restrict__ yb,
    float* __restrict__ ax, float* __restrict__ ay,
    float* __restrict__ gv, u32* __restrict__ flags)
{
  int rb = blockIdx.x;
  bool isY = rb >= N;
  int row = isY ? rb - N : rb;
  const float4* src = (const float4*)((isY ? y : x) + (size_t)row * D);
  u16* dst = (isY ? yb : xb) + (size_t)row * D;
  int t = threadIdx.x;

  if (rb == 0) ASTORE(&flags[t], 0u);   // reset all 256 flags (replay-safe)

  float4 v = src[t];
  float ss = v.x * v.x + v.y * v.y + v.z * v.z + v.w * v.w;
  ushort4 h;
  h.x = f2bf(v.x); h.y = f2bf(v.y); h.z = f2bf(v.z); h.w = f2bf(v.w);
  ((ushort4*)dst)[t] = h;

  #pragma unroll
  for (int o = 1; o < 64; o <<= 1) ss += __shfl_xor(ss, o, 64);
  __shared__ float sred[4];
  if ((t & 63) == 0) sred[t >> 6] = ss;
  __syncthreads();
  if (t == 0) {
    float a = (sred[0] + sred[1] + sred[2] + sred[3]) * L2E;
    if (isY) { ay[row] = a; ASTORE(&gv[row], LOG2A - a); }
    else     { ax[row] = a; }
  }
}

// ---- GEMM: Zq[i][j] = clamp(round(2*log2e*(A_i.B_j)/4)+128), bf16 MFMA 128x128
__global__ __launch_bounds__(256) void gemm_s(
    const u16* __restrict__ A, const u16* __restrict__ B, u8* __restrict__ out)
{
  __shared__ u16 As[128 * 64];
  __shared__ u16 Bs[128 * 64];
  const int t = threadIdx.x;
  const int lane = t & 63, w = t >> 6;
  const int wm = w >> 1, wn = w & 1;
  const int i0 = blockIdx.y * 128, j0 = blockIdx.x * 128;

  f32x4 acc[4][4] = {};

  for (int k0 = 0; k0 < D; k0 += 64) {
    #pragma unroll
    for (int q = 0; q < 4; ++q) {
      int lin = q * 256 + t;
      int row = lin >> 3, c8 = lin & 7;
      int cs = c8 ^ (row & 7);
      gload_lds16(A + (size_t)(i0 + row) * D + k0 + cs * 8, ((char*)As) + q * 4096 + w * 1024);
      gload_lds16(B + (size_t)(j0 + row) * D + k0 + cs * 8, ((char*)Bs) + q * 4096 + w * 1024);
    }
    __syncthreads();
    #pragma unroll
    for (int kk = 0; kk < 2; ++kk) {
      bf16x8 af[4], bfr[4];
      const int g = lane >> 4;
      #pragma unroll
      for (int fm = 0; fm < 4; ++fm) {
        int r = wm * 64 + fm * 16 + (lane & 15);
        af[fm] = *(const bf16x8*)(((const char*)As) + r * 128 + (((kk * 4 + g) ^ (r & 7)) * 16));
      }
      #pragma unroll
      for (int fn = 0; fn < 4; ++fn) {
        int r = wn * 64 + fn * 16 + (lane & 15);
        bfr[fn] = *(const bf16x8*)(((const char*)Bs) + r * 128 + (((kk * 4 + g) ^ (r & 7)) * 16));
      }
      #pragma unroll
      for (int fm = 0; fm < 4; ++fm)
        #pragma unroll
        for (int fn = 0; fn < 4; ++fn)
          acc[fm][fn] = __builtin_amdgcn_mfma_f32_16x16x32_bf16(af[fm], bfr[fn], acc[fm][fn], 0, 0, 0);
    }
    __syncthreads();
  }

  const float QS = 2.0f * L2E * 0.25f;   // acc * 2*log2e / 4
  #pragma unroll
  for (int fm = 0; fm < 4; ++fm)
    #pragma unroll
    for (int fn = 0; fn < 4; ++fn) {
      int gj = j0 + wn * 64 + fn * 16 + (lane & 15);
      #pragma unroll
      for (int r = 0; r < 4; ++r) {
        int gi = i0 + wm * 64 + fm * 16 + (lane >> 4) * 4 + r;
        int q = (int)rintf(acc[fm][fn][r] * QS) + 128;
        q = q < 0 ? 0 : (q > 255 ? 255 : q);
        out[(size_t)gi * N + gj] = (u8)q;
      }
    }
}

// process 16 cols of one chunk: vv[k] = 4*q_k + uu'_k, track max
static __device__ inline void chunk16(uint4 zz, const float* up, float* vv, float& m) {
  unsigned dw0 = zz.x, dw1 = zz.y, dw2 = zz.z, dw3 = zz.w;
  #pragma unroll
  for (int b = 0; b < 4; ++b) {
    unsigned d = (b == 0) ? dw0 : (b == 1) ? dw1 : (b == 2) ? dw2 : dw3;
    float v0 = fmaf((float)(d & 0xffu),         4.0f, up[b * 4 + 0]);
    float v1 = fmaf((float)((d >> 8) & 0xffu),  4.0f, up[b * 4 + 1]);
    float v2 = fmaf((float)((d >> 16) & 0xffu), 4.0f, up[b * 4 + 2]);
    float v3 = fmaf((float)(d >> 24),           4.0f, up[b * 4 + 3]);
    vv[b * 4 + 0] = v0; vv[b * 4 + 1] = v1; vv[b * 4 + 2] = v2; vv[b * 4 + 3] = v3;
    m = fmaxf(m, fmaxf(fmaxf(v0, v1), fmaxf(v2, v3)));
  }
}

// ---- persistent Sinkhorn, row-per-wave, flag-synced, int8 matrix
__global__ __launch_bounds__(1024, 4) void sinkhorn_persist(
    const u8* __restrict__ Zq, const u8* __restrict__ ZTq,
    const float* __restrict__ ax, const float* __restrict__ ay,
    float* __restrict__ fv, float* __restrict__ gv, float* __restrict__ pv,
    u32* __restrict__ flags, float* __restrict__ out)
{
  __shared__ float uu[4096 + 128];
  __shared__ float sred[16];
  const int t = threadIdx.x, blk = blockIdx.x;
  const int w = t >> 6, lane = t & 63;
  const int row = blk * 16 + w;                        // wave w owns row `row`
  const size_t zbase = (size_t)row * N + (lane << 4);  // bytes; chunks at +1024

  int ub[4];
  #pragma unroll
  for (int c = 0; c < 4; ++c) ub[c] = swz(c * 1024 + (lane << 4));

  uint4 zq[4];
  {
    const uint4* zp = (const uint4*)(Zq + zbase);
    #pragma unroll
    for (int c = 0; c < 4; ++c) zq[c] = zp[c * 64];
  }
  // stage phase-0 input (gv from prep; kernel boundary makes it visible)
  {
    u64 p0 = ALOAD((const u64*)&gv[4 * t]);
    u64 p1 = ALOAD((const u64*)&gv[4 * t + 2]);
    uu[swz(4 * t + 0)] = __uint_as_float((u32)p0)         - 512.0f;
    uu[swz(4 * t + 1)] = __uint_as_float((u32)(p0 >> 32)) - 512.0f;
    uu[swz(4 * t + 2)] = __uint_as_float((u32)p1)         - 512.0f;
    uu[swz(4 * t + 3)] = __uint_as_float((u32)(p1 >> 32)) - 512.0f;
  }
  __syncthreads();

  for (int ph = 0; ph < NPHASE; ++ph) {
    float* outv = (ph == NPHASE - 1) ? pv : ((ph & 1) ? gv : fv);
    const bool more = (ph + 1 < NPHASE);

    // compute row LSE from registers zq + LDS uu
    float vv[32];
    float mA = -3.0e38f;
    chunk16(zq[0], &uu[ub[0]], vv, mA);
    chunk16(zq[1], &uu[ub[1]], vv + 16, mA);
    float sA = 0.0f;
    #pragma unroll
    for (int k = 0; k < 32; ++k) sA += exp2f(vv[k] - mA);
    float mB = -3.0e38f;
    chunk16(zq[2], &uu[ub[2]], vv, mB);
    chunk16(zq[3], &uu[ub[3]], vv + 16, mB);
    float sB = 0.0f;
    #pragma unroll
    for (int k = 0; k < 32; ++k) sB += exp2f(vv[k] - mB);

    float m = fmaxf(mA, mB);
    float s = sA * exp2f(mA - m) + sB * exp2f(mB - m);
    #pragma unroll
    for (int o = 1; o < 64; o <<= 1) {
      float mo = __shfl_xor(m, o, 64);
      float so = __shfl_xor(s, o, 64);
      float mn = fmaxf(m, mo);
      s = s * exp2f(m - mn) + so * exp2f(mo - mn);
      m = mn;
    }
    if (lane == 0) ASTORE(&outv[row], LOG2A - (m + log2f(s)));

    if (more) {   // prefetch next phase's matrix slice (L2-resident)
      const u8* Mn = ((ph + 1) & 1) ? ZTq : Zq;
      const uint4* zp = (const uint4*)(Mn + zbase);
      #pragma unroll
      for (int c = 0; c < 4; ++c) zq[c] = zp[c * 64];
    }

    __syncthreads();   // drains value-store acks (vmcnt0) for all 16 waves
    if (t == 0) ASTORE(&flags[blk], (u32)(ph + 1));

    if (more) {
      if (w == 0) {    // only wave 0 polls: 64 lanes x 4 flags = 256
        const u32 tgt = (u32)(ph + 1);
        for (;;) {
          u64 a = ALOAD((const u64*)&flags[lane * 4]);
          u64 b = ALOAD((const u64*)&flags[lane * 4 + 2]);
          bool ok = ((u32)a >= tgt) & ((u32)(a >> 32) >= tgt)
                  & ((u32)b >= tgt) & ((u32)(b >> 32) >= tgt);
          if (__all(ok)) break;
          __builtin_amdgcn_s_sleep(1);
        }
      }
      __syncthreads();  // verdict: all inputs published

      const float* src = ((ph + 1) & 1) ? fv : gv;
      u64 p0 = ALOAD((const u64*)&src[4 * t]);
      u64 p1 = ALOAD((const u64*)&src[4 * t + 2]);
      uu[swz(4 * t + 0)] = __uint_as_float((u32)p0)         - 512.0f;
      uu[swz(4 * t + 1)] = __uint_as_float((u32)(p0 >> 32)) - 512.0f;
      uu[swz(4 * t + 2)] = __uint_as_float((u32)p1)         - 512.0f;
      uu[swz(4 * t + 3)] = __uint_as_float((u32)(p1 >> 32)) - 512.0f;
      __syncthreads();  // uu ready for next phase
    }
  }

  // finalize: block 0 waits for all flags==NPHASE, then gathers
  if (blk == 0) {
    if (t < NBLK) {
      while (ALOAD(&flags[t]) < (u32)NPHASE) __builtin_amdgcn_s_sleep(1);
    }
    __syncthreads();
    float acc = 0.0f;
    #pragma unroll
    for (int rep = 0; rep < 4; ++rep) {
      int i = (rep << 10) + t;
      float fc = ALOAD(&fv[i]);
      float gc = ALOAD(&gv[i]);
      float pp = ALOAD(&pv[i]);
      acc += exp2f(fc - pp) * (fc + ax[i] - LOG2A);
      acc += gc + ay[i] - LOG2A;
    }
    #pragma unroll
    for (int o = 1; o < 64; o <<= 1) acc += __shfl_xor(acc, o, 64);
    if ((t & 63) == 0) sred[t >> 6] = acc;
    __syncthreads();
    if (t == 0) {
      float tot = 0.0f;
      #pragma unroll
      for (int k = 0; k < 16; ++k) tot += sred[k];
      const float LN2 = 0.6931471805599453f;
      out[0] = tot * (LN2 / ((float)N * (float)D));
    }
  }
}

extern "C" void kernel_launch(void* const* d_in, const int* in_sizes, int n_in,
                              void* d_out, int out_size, void* d_ws, size_t ws_size,
                              hipStream_t stream) {
  const float* x = (const float*)d_in[0];
  const float* y = (const float*)d_in[1];
  float* out = (float*)d_out;
  char* ws = (char*)d_ws;

  const size_t SZ_Q  = (size_t)N * N * sizeof(u8);    // 16 MiB
  const size_t SZ_BF = (size_t)N * D * sizeof(u16);   // 8 MiB
  const size_t SZ_V  = (size_t)N * sizeof(float);     // 16 KiB

  u8*  Zq  = (u8*)(ws);
  u8*  ZTq = (u8*)(ws + SZ_Q);
  u16* xb  = (u16*)(ws + 2 * SZ_Q);
  u16* yb  = (u16*)(ws + 2 * SZ_Q + SZ_BF);
  char* vb = ws + 2 * SZ_Q + 2 * SZ_BF;
  float* ax  = (float*)(vb + 0 * SZ_V);
  float* ay  = (float*)(vb + 1 * SZ_V);
  float* fvv = (float*)(vb + 2 * SZ_V);
  float* gvv = (float*)(vb + 3 * SZ_V);
  float* pvv = (float*)(vb + 4 * SZ_V);
  u32* flags = (u32*)(vb + 5 * SZ_V);

  prep_kernel<<<2 * N, 256, 0, stream>>>(x, y, xb, yb, ax, ay, gvv, flags);

  dim3 gg(N / 128, N / 128, 1);
  gemm_s<<<gg, 256, 0, stream>>>(xb, yb, Zq);
  gemm_s<<<gg, 256, 0, stream>>>(yb, xb, ZTq);

  sinkhorn_persist<<<NBLK, 1024, 0, stream>>>(Zq, ZTq, ax, ay, fvv, gvv, pvv, flags, out);
}

// Round 9
// 1268.127 us; speedup vs baseline: 2.3031x; 1.6248x over previous
//
#include <hip/hip_runtime.h>
#include <hip/hip_bf16.h>

// Sinkhorn entropic OT (reg=1, 100 iters), persistent kernel, int8 L2-resident
// cost matrix, per-block flag dataflow sync.
//   Zq = round(2*log2e*(x.yT)/4)+128 (u8, 16MiB), ZTq likewise. Z = 4*q - 512.
//   f: fcore_i = LOG2A - log2 sum_j 2^(gcore_j + Z_ij)     (even phases)
//   g: gcore_j = LOG2A - log2 sum_i 2^(fcore_i + ZT_ji)    (odd phases)
// Per phase: publish 16 fp32 (relaxed agent) -> __syncthreads (drain acks) ->
// t0 flag[blk]=ph+1 -> issue NEXT zq loads (latency hides under poll) ->
// wave-parallel poll (wave w owns flags[16w..16w+15]) -> barrier -> one-shot
// value reads -> LDS -> barrier. Causality: flag(ph+1) follows staging of
// input(ph) in program order => skew < 2 phases => single buffer race-free.
// out = ln2/(N*D) * [ sum_i 2^(fcore-php)*(fcore+ax-LOG2A) + sum_j (gcore+ay-LOG2A) ]

#define N 4096
#define D 1024
#define L2E 1.4426950408889634f
#define LOG2A (-12.0f)
#define NBLK 256
#define NPHASE 201   // 100*(f,g) + final f (row marginals)

typedef unsigned char u8;
typedef unsigned short u16;
typedef unsigned u32;
typedef unsigned long long u64;
typedef __attribute__((ext_vector_type(8))) short bf16x8;
typedef __attribute__((ext_vector_type(4))) float f32x4;

#define ALOAD(p)     __hip_atomic_load((p), __ATOMIC_RELAXED, __HIP_MEMORY_SCOPE_AGENT)
#define ASTORE(p, v) __hip_atomic_store((p), (v), __ATOMIC_RELAXED, __HIP_MEMORY_SCOPE_AGENT)

static __device__ inline float ex2(float x) {
#if __has_builtin(__builtin_amdgcn_exp2f)
  return __builtin_amdgcn_exp2f(x);
#else
  float r; asm("v_exp_f32 %0, %1" : "=v"(r) : "v"(x)); return r;
#endif
}
static __device__ inline float lg2(float x) {
#if __has_builtin(__builtin_amdgcn_logf)
  return __builtin_amdgcn_logf(x);
#else
  float r; asm("v_log_f32 %0, %1" : "=v"(r) : "v"(x)); return r;
#endif
}

static __device__ inline u16 f2bf(float f) {
  unsigned u = __float_as_uint(f);
  unsigned r = (u + 0x7FFFu + ((u >> 16) & 1u)) >> 16;
  return (u16)r;
}

static __device__ inline void gload_lds16(const void* g, void* l) {
  __builtin_amdgcn_global_load_lds(
      (const __attribute__((address_space(1))) void*)g,
      (__attribute__((address_space(3))) void*)l, 16, 0, 0);
}

static __device__ inline int swz(int col) { return col + (col >> 5); }

// ---- prep: row sum-of-squares + fp32->bf16 + ax/ay/gv init + flag reset
__global__ __launch_bounds__(256) void prep_kernel(
    const float* __restrict__ x, const float* __restrict__ y,
    u16* __restrict__ xb, u16* __restrict__ yb,
    float* __restrict__ ax, float* __restrict__ ay,
    float* __restrict__ gv, u32* __restrict__ flags)
{
  int rb = blockIdx.x;
  bool isY = rb >= N;
  int row = isY ? rb - N : rb;
  const float4* src = (const float4*)((isY ? y : x) + (size_t)row * D);
  u16* dst = (isY ? yb : xb) + (size_t)row * D;
  int t = threadIdx.x;

  if (rb == 0) ASTORE(&flags[t], 0u);   // reset all 256 flags (replay-safe)

  float4 v = src[t];
  float ss = v.x * v.x + v.y * v.y + v.z * v.z + v.w * v.w;
  ushort4 h;
  h.x = f2bf(v.x); h.y = f2bf(v.y); h.z = f2bf(v.z); h.w = f2bf(v.w);
  ((ushort4*)dst)[t] = h;

  #pragma unroll
  for (int o = 1; o < 64; o <<= 1) ss += __shfl_xor(ss, o, 64);
  __shared__ float sred[4];
  if ((t & 63) == 0) sred[t >> 6] = ss;
  __syncthreads();
  if (t == 0) {
    float a = (sred[0] + sred[1] + sred[2] + sred[3]) * L2E;
    if (isY) { ay[row] = a; ASTORE(&gv[row], LOG2A - a); }
    else     { ax[row] = a; }
  }
}

// ---- GEMM: Zq[i][j] = clamp(round(2*log2e*(A_i.B_j)/4)+128), bf16 MFMA 128x128
__global__ __launch_bounds__(256) void gemm_s(
    const u16* __restrict__ A, const u16* __restrict__ B, u8* __restrict__ out)
{
  __shared__ u16 As[128 * 64];
  __shared__ u16 Bs[128 * 64];
  const int t = threadIdx.x;
  const int lane = t & 63, w = t >> 6;
  const int wm = w >> 1, wn = w & 1;
  const int i0 = blockIdx.y * 128, j0 = blockIdx.x * 128;

  f32x4 acc[4][4] = {};

  for (int k0 = 0; k0 < D; k0 += 64) {
    #pragma unroll
    for (int q = 0; q < 4; ++q) {
      int lin = q * 256 + t;
      int row = lin >> 3, c8 = lin & 7;
      int cs = c8 ^ (row & 7);
      gload_lds16(A + (size_t)(i0 + row) * D + k0 + cs * 8, ((char*)As) + q * 4096 + w * 1024);
      gload_lds16(B + (size_t)(j0 + row) * D + k0 + cs * 8, ((char*)Bs) + q * 4096 + w * 1024);
    }
    __syncthreads();
    #pragma unroll
    for (int kk = 0; kk < 2; ++kk) {
      bf16x8 af[4], bfr[4];
      const int g = lane >> 4;
      #pragma unroll
      for (int fm = 0; fm < 4; ++fm) {
        int r = wm * 64 + fm * 16 + (lane & 15);
        af[fm] = *(const bf16x8*)(((const char*)As) + r * 128 + (((kk * 4 + g) ^ (r & 7)) * 16));
      }
      #pragma unroll
      for (int fn = 0; fn < 4; ++fn) {
        int r = wn * 64 + fn * 16 + (lane & 15);
        bfr[fn] = *(const bf16x8*)(((const char*)Bs) + r * 128 + (((kk * 4 + g) ^ (r & 7)) * 16));
      }
      #pragma unroll
      for (int fm = 0; fm < 4; ++fm)
        #pragma unroll
        for (int fn = 0; fn < 4; ++fn)
          acc[fm][fn] = __builtin_amdgcn_mfma_f32_16x16x32_bf16(af[fm], bfr[fn], acc[fm][fn], 0, 0, 0);
    }
    __syncthreads();
  }

  const float QS = 2.0f * L2E * 0.25f;   // acc * 2*log2e / 4
  #pragma unroll
  for (int fm = 0; fm < 4; ++fm)
    #pragma unroll
    for (int fn = 0; fn < 4; ++fn) {
      int gj = j0 + wn * 64 + fn * 16 + (lane & 15);
      #pragma unroll
      for (int r = 0; r < 4; ++r) {
        int gi = i0 + wm * 64 + fm * 16 + (lane >> 4) * 4 + r;
        int q = (int)rintf(acc[fm][fn][r] * QS) + 128;
        q = q < 0 ? 0 : (q > 255 ? 255 : q);
        out[(size_t)gi * N + gj] = (u8)q;
      }
    }
}

// process 16 cols of one chunk: vv[k] = 4*q_k + uu'_k, track max
static __device__ inline void chunk16(uint4 zz, const float* up, float* vv, float& m) {
  unsigned dw0 = zz.x, dw1 = zz.y, dw2 = zz.z, dw3 = zz.w;
  #pragma unroll
  for (int b = 0; b < 4; ++b) {
    unsigned d = (b == 0) ? dw0 : (b == 1) ? dw1 : (b == 2) ? dw2 : dw3;
    float v0 = fmaf((float)(d & 0xffu),         4.0f, up[b * 4 + 0]);
    float v1 = fmaf((float)((d >> 8) & 0xffu),  4.0f, up[b * 4 + 1]);
    float v2 = fmaf((float)((d >> 16) & 0xffu), 4.0f, up[b * 4 + 2]);
    float v3 = fmaf((float)(d >> 24),           4.0f, up[b * 4 + 3]);
    vv[b * 4 + 0] = v0; vv[b * 4 + 1] = v1; vv[b * 4 + 2] = v2; vv[b * 4 + 3] = v3;
    m = fmaxf(m, fmaxf(fmaxf(v0, v1), fmaxf(v2, v3)));
  }
}

// ---- persistent Sinkhorn, row-per-wave, flag-synced, int8 matrix
__global__ __launch_bounds__(1024, 4) void sinkhorn_persist(
    const u8* __restrict__ Zq, const u8* __restrict__ ZTq,
    const float* __restrict__ ax, const float* __restrict__ ay,
    float* __restrict__ fv, float* __restrict__ gv, float* __restrict__ pv,
    u32* __restrict__ flags, float* __restrict__ out)
{
  __shared__ float uu[4096 + 128];
  __shared__ float sred[16];
  const int t = threadIdx.x, blk = blockIdx.x;
  const int w = t >> 6, lane = t & 63;
  const int row = blk * 16 + w;                        // wave w owns row `row`
  const size_t zbase = (size_t)row * N + (lane << 4);  // bytes; chunks at +1024

  int ub[4];
  #pragma unroll
  for (int c = 0; c < 4; ++c) ub[c] = swz(c * 1024 + (lane << 4));

  uint4 zq[4];
  {
    const uint4* zp = (const uint4*)(Zq + zbase);
    #pragma unroll
    for (int c = 0; c < 4; ++c) zq[c] = zp[c * 64];
  }
  // stage phase-0 input (gv from prep; kernel boundary makes it visible)
  {
    u64 p0 = ALOAD((const u64*)&gv[4 * t]);
    u64 p1 = ALOAD((const u64*)&gv[4 * t + 2]);
    uu[swz(4 * t + 0)] = __uint_as_float((u32)p0)         - 512.0f;
    uu[swz(4 * t + 1)] = __uint_as_float((u32)(p0 >> 32)) - 512.0f;
    uu[swz(4 * t + 2)] = __uint_as_float((u32)p1)         - 512.0f;
    uu[swz(4 * t + 3)] = __uint_as_float((u32)(p1 >> 32)) - 512.0f;
  }
  __syncthreads();

  for (int ph = 0; ph < NPHASE; ++ph) {
    float* outv = (ph == NPHASE - 1) ? pv : ((ph & 1) ? gv : fv);
    const bool more = (ph + 1 < NPHASE);

    // compute row LSE from registers zq + LDS uu
    float vv[32];
    float mA = -3.0e38f;
    chunk16(zq[0], &uu[ub[0]], vv, mA);
    chunk16(zq[1], &uu[ub[1]], vv + 16, mA);
    float sA = 0.0f;
    #pragma unroll
    for (int k = 0; k < 32; ++k) sA += ex2(vv[k] - mA);
    float mB = -3.0e38f;
    chunk16(zq[2], &uu[ub[2]], vv, mB);
    chunk16(zq[3], &uu[ub[3]], vv + 16, mB);
    float sB = 0.0f;
    #pragma unroll
    for (int k = 0; k < 32; ++k) sB += ex2(vv[k] - mB);

    float m = fmaxf(mA, mB);
    float s = sA * ex2(mA - m) + sB * ex2(mB - m);
    #pragma unroll
    for (int o = 1; o < 64; o <<= 1) {
      float mo = __shfl_xor(m, o, 64);
      float so = __shfl_xor(s, o, 64);
      float mn = fmaxf(m, mo);
      s = s * ex2(m - mn) + so * ex2(mo - mn);
      m = mn;
    }
    if (lane == 0) ASTORE(&outv[row], LOG2A - (m + lg2(s)));

    __syncthreads();   // drains value-store acks (vmcnt0); zq loads NOT pending
    if (t == 0) ASTORE(&flags[blk], (u32)(ph + 1));

    if (more) {
      // issue next phase's matrix loads NOW — latency hides under the poll
      const u8* Mn = ((ph + 1) & 1) ? ZTq : Zq;
      const uint4* zp = (const uint4*)(Mn + zbase);
      #pragma unroll
      for (int c = 0; c < 4; ++c) zq[c] = zp[c * 64];

      // wave-parallel poll: wave w watches flags[16w..16w+15] via lanes 0-15
      const u32 tgt = (u32)(ph + 1);
      for (;;) {
        bool ok = (lane < 16) ? (ALOAD(&flags[w * 16 + lane]) >= tgt) : true;
        if (__all(ok)) break;
        __builtin_amdgcn_s_sleep(1);
      }
      __syncthreads();  // all 16 wave-verdicts in: every input published

      const float* src = ((ph + 1) & 1) ? fv : gv;
      u64 p0 = ALOAD((const u64*)&src[4 * t]);
      u64 p1 = ALOAD((const u64*)&src[4 * t + 2]);
      uu[swz(4 * t + 0)] = __uint_as_float((u32)p0)         - 512.0f;
      uu[swz(4 * t + 1)] = __uint_as_float((u32)(p0 >> 32)) - 512.0f;
      uu[swz(4 * t + 2)] = __uint_as_float((u32)p1)         - 512.0f;
      uu[swz(4 * t + 3)] = __uint_as_float((u32)(p1 >> 32)) - 512.0f;
      __syncthreads();  // uu ready for next phase
    }
  }

  // finalize: block 0 waits for all flags==NPHASE, then gathers
  if (blk == 0) {
    if (t < NBLK) {
      while (ALOAD(&flags[t]) < (u32)NPHASE) __builtin_amdgcn_s_sleep(1);
    }
    __syncthreads();
    float acc = 0.0f;
    #pragma unroll
    for (int rep = 0; rep < 4; ++rep) {
      int i = (rep << 10) + t;
      float fc = ALOAD(&fv[i]);
      float gc = ALOAD(&gv[i]);
      float pp = ALOAD(&pv[i]);
      acc += ex2(fc - pp) * (fc + ax[i] - LOG2A);
      acc += gc + ay[i] - LOG2A;
    }
    #pragma unroll
    for (int o = 1; o < 64; o <<= 1) acc += __shfl_xor(acc, o, 64);
    if ((t & 63) == 0) sred[t >> 6] = acc;
    __syncthreads();
    if (t == 0) {
      float tot = 0.0f;
      #pragma unroll
      for (int k = 0; k < 16; ++k) tot += sred[k];
      const float LN2 = 0.6931471805599453f;
      out[0] = tot * (LN2 / ((float)N * (float)D));
    }
  }
}

extern "C" void kernel_launch(void* const* d_in, const int* in_sizes, int n_in,
                              void* d_out, int out_size, void* d_ws, size_t ws_size,
                              hipStream_t stream) {
  const float* x = (const float*)d_in[0];
  const float* y = (const float*)d_in[1];
  float* out = (float*)d_out;
  char* ws = (char*)d_ws;

  const size_t SZ_Q  = (size_t)N * N * sizeof(u8);    // 16 MiB
  const size_t SZ_BF = (size_t)N * D * sizeof(u16);   // 8 MiB
  const size_t SZ_V  = (size_t)N * sizeof(float);     // 16 KiB

  u8*  Zq  = (u8*)(ws);
  u8*  ZTq = (u8*)(ws + SZ_Q);
  u16* xb  = (u16*)(ws + 2 * SZ_Q);
  u16* yb  = (u16*)(ws + 2 * SZ_Q + SZ_BF);
  char* vb = ws + 2 * SZ_Q + 2 * SZ_BF;
  float* ax  = (float*)(vb + 0 * SZ_V);
  float* ay  = (float*)(vb + 1 * SZ_V);
  float* fvv = (float*)(vb + 2 * SZ_V);
  float* gvv = (float*)(vb + 3 * SZ_V);
  float* pvv = (float*)(vb + 4 * SZ_V);
  u32* flags = (u32*)(vb + 5 * SZ_V);

  prep_kernel<<<2 * N, 256, 0, stream>>>(x, y, xb, yb, ax, ay, gvv, flags);

  dim3 gg(N / 128, N / 128, 1);
  gemm_s<<<gg, 256, 0, stream>>>(xb, yb, Zq);
  gemm_s<<<gg, 256, 0, stream>>>(yb, xb, ZTq);

  sinkhorn_persist<<<NBLK, 1024, 0, stream>>>(Zq, ZTq, ax, ay, fvv, gvv, pvv, flags, out);
}